// Round 9
// baseline (262.589 us; speedup 1.0000x reference)
//
#include <hip/hip_runtime.h>
#include <hip/hip_fp16.h>

// Fused 8-step diffusion, v10: v8 base + validity-horizon skip + intra-wave
// shuffle exchange.
//
// v9 post-mortem: 1.25x-halo geometry was eaten by VGPR=128 spill (+4MB
// scratch) + 53KB LDS + whL round-trips -> 93us vs v8's 88.2. v8 geometry is
// the frontier; its split: load ~50us (near the ~4.75-6.7TB/s service floor),
// step ~35us vs ~10us pure VALU -> step phase is furthest from floor.
//
// v10 changes vs v8 (sync structure untouched -- two barriers/step):
//  1. VALIDITY-HORIZON SKIP: halo row at distance d from the owned 32-row
//     region only needs computing at steps s with s+d<=7. Skip dead row
//     computes (-19% step FMA); edge waves skip whole step bodies and reach
//     the barrier early (shrinks lockstep convoy). dist-8 rows are never
//     computed -> skip their weight loads (-3% weight bytes). Pad rows are
//     never computed -> re-zero pass deleted (init-0 suffices). All consumed
//     values bitwise-identical to v8.
//  2. INTRA-WAVE EXCHANGE: wave = rg pair (2w,2w+1); their shared boundary
//     moves via __shfl_xor(.,32) instead of LDS. Only inter-wave boundaries
//     use LDS -> exchange traffic halved, single 8KB buffer (even rg
//     publishes top row, odd rg publishes bottom row; disjoint slots).
//
// Carried from v8: 1024 blocks = 4/plane (48-row window = 32 owned + 8 halo
// each side), 512 threads, 3 rows x 4 cols/thread, k-outer independent
// weight stream packed |.| fp16 unnormalized + register normalize post-pass,
// x loads hoisted, XCD-chunked bijective swizzle, plain launch_bounds(512)
// (only shape escaping the 64-VGPR allocator trap).

constexpr int H = 128, W = 128, PLANE = H * W;
constexpr int NSTEP = 8;
constexpr int RPT  = 3;            // rows per thread (48-row window / 16 rg)
constexpr int NRG  = 16;
constexpr int HALO = 8;
constexpr int OWN  = 32;           // owned rows per block (4 blocks/plane)

// 6-wide column window (cols j0-1 .. j0+4) from a float4 row segment
#define MKWIN(D, V) do {                                                     \
    (D)[1] = (V).x; (D)[2] = (V).y; (D)[3] = (V).z; (D)[4] = (V).w;          \
    float _l = __shfl_up((V).w, 1);                                          \
    float _r = __shfl_down((V).x, 1);                                        \
    (D)[0] = (quad == 0)  ? 0.f : _l;                                        \
    (D)[5] = (quad == 31) ? 0.f : _r;                                        \
} while (0)

__device__ __forceinline__ float4 shflx32(float4 v) {
    float4 r;
    r.x = __shfl_xor(v.x, 32);
    r.y = __shfl_xor(v.y, 32);
    r.z = __shfl_xor(v.z, 32);
    r.w = __shfl_xor(v.w, 32);
    return r;
}

__global__ __launch_bounds__(512)
void diff_fused(const float* __restrict__ xin,
                const float* __restrict__ wgt,
                float* __restrict__ out)
{
    // exchange buffer: even rg slots hold its TOP row, odd rg slots hold its
    // BOTTOM row (each rg writes only its own slot -> disjoint).  8 KB.
    __shared__ float ldsX[NRG][W];

    const int tid   = threadIdx.x;
    const int quad  = tid & 31;         // cols 4q..4q+3
    const int rg    = tid >> 5;         // 0..15
    const int j0    = quad * 4;

    // XCD-chunked swizzle: hw block i -> logical (i&7)*128 + (i>>3).
    const int lb    = (blockIdx.x & 7) * 128 + (blockIdx.x >> 3);
    const int plane = lb >> 2;
    const int qtr   = lb & 3;
    const int rbase = qtr * OWN - HALO;         // window start row
    const int r0    = rbase + rg * RPT;         // this thread's first row
    const int own_lo = qtr * OWN;
    const int own_hi = own_lo + OWN - 1;
    const size_t pbase = (size_t)plane * PLANE;

    const float* __restrict__ xp = xin + pbase;
    const float* __restrict__ wb = wgt + pbase * 9;

    // per-row distance to owned region + in-plane flag
    int  dist[RPT];
    bool inr [RPT];
    int  mind = 99;                     // min dist over in-plane rows
    #pragma unroll
    for (int p = 0; p < RPT; ++p) {
        const int gr = r0 + p;
        inr[p] = (unsigned)gr < (unsigned)H;
        int d = 0;
        if (gr < own_lo)      d = own_lo - gr;
        else if (gr > own_hi) d = gr - own_hi;
        dist[p] = d;
        if (inr[p] && d < mind) mind = d;
    }

    // ---- x window first (independent misses in flight early) ----
    float4 xr[RPT];
    #pragma unroll
    for (int p = 0; p < RPT; ++p) {
        xr[p] = make_float4(0.f, 0.f, 0.f, 0.f);
        if (inr[p])
            xr[p] = *reinterpret_cast<const float4*>(xp + (r0 + p) * W + j0);
    }

    // ---- weights: k-outer independent stream, pack |.| fp16 UNNORMALIZED,
    //      fp32 sums on the side; register-only normalize post-pass.
    //      dist-8 rows are never computed -> skip their loads. ----
    __half2 wh[RPT][9][2];              // 54 VGPRs
    float s[RPT][4];
    #pragma unroll
    for (int p = 0; p < RPT; ++p) { s[p][0] = s[p][1] = s[p][2] = s[p][3] = 0.f; }

    #pragma unroll
    for (int k = 0; k < 9; ++k) {
        float4 v[RPT];
        #pragma unroll
        for (int p = 0; p < RPT; ++p) {
            v[p] = make_float4(1.f, 1.f, 1.f, 1.f);      // dummy (unused rows)
            if (inr[p] && dist[p] <= 7)
                v[p] = *reinterpret_cast<const float4*>(
                           wb + (size_t)k * PLANE + (r0 + p) * W + j0);
        }
        #pragma unroll
        for (int p = 0; p < RPT; ++p) {
            const float a0 = fabsf(v[p].x), a1 = fabsf(v[p].y);
            const float a2 = fabsf(v[p].z), a3 = fabsf(v[p].w);
            s[p][0] += a0; s[p][1] += a1; s[p][2] += a2; s[p][3] += a3;
            wh[p][k][0] = __halves2half2(__float2half_rn(a0), __float2half_rn(a1));
            wh[p][k][1] = __halves2half2(__float2half_rn(a2), __float2half_rn(a3));
        }
    }
    #pragma unroll
    for (int p = 0; p < RPT; ++p) {
        const float i0 = 1.f / s[p][0], i1 = 1.f / s[p][1];
        const float i2 = 1.f / s[p][2], i3 = 1.f / s[p][3];
        #pragma unroll
        for (int k = 0; k < 9; ++k) {
            wh[p][k][0] = __halves2half2(
                __float2half_rn(__low2float (wh[p][k][0]) * i0),
                __float2half_rn(__high2float(wh[p][k][0]) * i1));
            wh[p][k][1] = __halves2half2(
                __float2half_rn(__low2float (wh[p][k][1]) * i2),
                __float2half_rn(__high2float(wh[p][k][1]) * i3));
        }
    }

    // ---- 8 fused steps; two barriers/step (v3's single-barrier raced) ----
    #pragma unroll 1
    for (int st = 0; st < NSTEP; ++st) {
        // publish: even rg -> its top row; odd rg -> its bottom row
        *reinterpret_cast<float4*>(&ldsX[rg][j0]) =
            (rg & 1) ? xr[RPT - 1] : xr[0];
        __syncthreads();

        // intra-wave boundary via shuffle (rg pair shares a 64-lane wave)
        const float4 swT = shflx32(xr[0]);        // odd->even: rg+1's top
        const float4 swB = shflx32(xr[RPT - 1]);  // even->odd: rg-1's bottom
        float4 up = make_float4(0.f, 0.f, 0.f, 0.f);
        float4 dn = make_float4(0.f, 0.f, 0.f, 0.f);
        if (rg & 1) {
            up = swB;
            if (rg < NRG - 1)
                dn = *reinterpret_cast<const float4*>(&ldsX[rg + 1][j0]);
        } else {
            dn = swT;
            if (rg > 0)
                up = *reinterpret_cast<const float4*>(&ldsX[rg - 1][j0]);
        }
        __syncthreads();   // reads done before next step's writes

        // validity-horizon skip: row gr needs computing at step st iff
        // dist(gr)+st <= 7 (and in-plane). Whole-thread skip when even the
        // closest row fails -> edge waves reach the barrier early.
        if (st + mind <= 7) {
            float win[3][6];
            MKWIN(win[0], up);       // input row r0-1
            MKWIN(win[1], xr[0]);    // input row r0
            #pragma unroll
            for (int p = 0; p < RPT; ++p) {
                if (p < RPT - 1) { MKWIN(win[(p + 2) % 3], xr[p + 1]); }
                else             { MKWIN(win[(p + 2) % 3], dn); }
                if (inr[p] && st + dist[p] <= 7) {
                    float a0 = 0.f, a1 = 0.f, a2 = 0.f, a3 = 0.f;
                    #pragma unroll
                    for (int di = 0; di < 3; ++di) {
                        #pragma unroll
                        for (int dj = 0; dj < 3; ++dj) {
                            const int k = di * 3 + dj;
                            const __half2 w0 = wh[p][k][0];
                            const __half2 w1 = wh[p][k][1];
                            a0 = fmaf(__low2float (w0), win[(p + di) % 3][dj + 0], a0);
                            a1 = fmaf(__high2float(w0), win[(p + di) % 3][dj + 1], a1);
                            a2 = fmaf(__low2float (w1), win[(p + di) % 3][dj + 2], a2);
                            a3 = fmaf(__high2float(w1), win[(p + di) % 3][dj + 3], a3);
                        }
                    }
                    xr[p] = make_float4(a0, a1, a2, a3);
                }
            }
        }
    }

    // ---- store owned rows only (dist==0), coalesced float4 ----
    float* __restrict__ op = out + pbase;
    #pragma unroll
    for (int p = 0; p < RPT; ++p) {
        const int gr = r0 + p;
        const int lr = gr - own_lo;
        if ((unsigned)lr < (unsigned)OWN)
            *reinterpret_cast<float4*>(op + gr * W + j0) = xr[p];
    }
}

extern "C" void kernel_launch(void* const* d_in, const int* in_sizes, int n_in,
                              void* d_out, int out_size, void* d_ws, size_t ws_size,
                              hipStream_t stream)
{
    const float* x = (const float*)d_in[0];
    const float* w = (const float*)d_in[1];
    float* out = (float*)d_out;
    (void)d_ws; (void)ws_size; (void)in_sizes; (void)n_in; (void)out_size;

    // 1024 blocks = 4 per plane (4n x 64c), 512 threads
    diff_fused<<<dim3(4 * 4 * 64), dim3(512), 0, stream>>>(x, w, out);
}

// Round 10
// 249.018 us; speedup vs baseline: 1.0545x; 1.0545x over previous
//
#include <hip/hip_runtime.h>
#include <hip/hip_fp16.h>

// Fused 8-step diffusion, v11: v8 exact + compute moved inside the
// read-protected barrier region (the only change).
//
// v10 post-mortem (105us, REGRESSION): wave = rg-PAIR on this layout, so
// if(rg&1) exchange and per-row horizon checks diverged inside every wave
// -> both branch sides executed serially + FMA-block scheduling broke.
// Reverted entirely.
//
// v11 vs v8: step loop order was publish,bar,read,bar,compute;
// now publish,bar,read,COMPUTE,bar. Same two-barrier guarantees (reads are
// consumed by compute -> drained before the barrier that precedes the next
// publish), but waves that finish LDS reads early start computing instead
// of idling at barrier 2 -> VALU issue de-clusters, barrier absorbs the
// variance. Last step: trailing barrier dropped (nothing reads after).
//
// Carried from v8 (88.2us frontier): 1024 blocks = 4/plane (48-row window =
// 32 owned + 8 halo each side), 512 threads, 3 rows x 4 cols/thread,
// k-outer independent weight stream packed |.| fp16 unnormalized + register
// normalize post-pass, x loads hoisted, XCD-chunked bijective swizzle,
// plain launch_bounds(512) (only shape escaping the 64-VGPR allocator trap).

constexpr int H = 128, W = 128, PLANE = H * W;
constexpr int NSTEP = 8;
constexpr int RPT  = 3;            // rows per thread (48-row window / 16 rg)
constexpr int NRG  = 16;
constexpr int HALO = 8;
constexpr int OWN  = 32;           // owned rows per block (4 blocks/plane)

// 6-wide column window (cols j0-1 .. j0+4) from a float4 row segment
#define MKWIN(D, V) do {                                                     \
    (D)[1] = (V).x; (D)[2] = (V).y; (D)[3] = (V).z; (D)[4] = (V).w;          \
    float _l = __shfl_up((V).w, 1);                                          \
    float _r = __shfl_down((V).x, 1);                                        \
    (D)[0] = (quad == 0)  ? 0.f : _l;                                        \
    (D)[5] = (quad == 31) ? 0.f : _r;                                        \
} while (0)

__global__ __launch_bounds__(512)
void diff_fused(const float* __restrict__ xin,
                const float* __restrict__ wgt,
                float* __restrict__ out)
{
    __shared__ float ldsT[NRG][W];      // each rg's top row    (8 KB)
    __shared__ float ldsB[NRG][W];      // each rg's bottom row (8 KB)

    const int tid   = threadIdx.x;
    const int quad  = tid & 31;         // cols 4q..4q+3
    const int rg    = tid >> 5;         // 0..15
    const int j0    = quad * 4;

    // XCD-chunked swizzle: hw block i -> logical (i&7)*128 + (i>>3).
    const int lb    = (blockIdx.x & 7) * 128 + (blockIdx.x >> 3);
    const int plane = lb >> 2;
    const int qtr   = lb & 3;
    const int rbase = qtr * OWN - HALO;         // window start row
    const int r0    = rbase + rg * RPT;         // this thread's first row
    const size_t pbase = (size_t)plane * PLANE;

    const float* __restrict__ xp = xin + pbase;
    const float* __restrict__ wb = wgt + pbase * 9;

    // ---- x window first: 3 independent misses in flight early ----
    float4 xr[RPT];
    #pragma unroll
    for (int p = 0; p < RPT; ++p) {
        const int gr = r0 + p;
        xr[p] = make_float4(0.f, 0.f, 0.f, 0.f);
        if ((unsigned)gr < (unsigned)H)
            xr[p] = *reinterpret_cast<const float4*>(xp + gr * W + j0);
    }

    // ---- weights: k-outer, pack |.| fp16 UNNORMALIZED as loads arrive,
    //      fp32 sums on the side; register-only normalize post-pass. ----
    __half2 wh[RPT][9][2];              // 54 VGPRs
    float s[RPT][4];
    #pragma unroll
    for (int p = 0; p < RPT; ++p) { s[p][0] = s[p][1] = s[p][2] = s[p][3] = 0.f; }

    #pragma unroll
    for (int k = 0; k < 9; ++k) {
        float4 v[RPT];
        #pragma unroll
        for (int p = 0; p < RPT; ++p) {
            const int gr = r0 + p;
            v[p] = make_float4(1.f, 1.f, 1.f, 1.f);      // dummy for pad rows
            if ((unsigned)gr < (unsigned)H)
                v[p] = *reinterpret_cast<const float4*>(
                           wb + (size_t)k * PLANE + gr * W + j0);
        }
        #pragma unroll
        for (int p = 0; p < RPT; ++p) {
            const float a0 = fabsf(v[p].x), a1 = fabsf(v[p].y);
            const float a2 = fabsf(v[p].z), a3 = fabsf(v[p].w);
            s[p][0] += a0; s[p][1] += a1; s[p][2] += a2; s[p][3] += a3;
            wh[p][k][0] = __halves2half2(__float2half_rn(a0), __float2half_rn(a1));
            wh[p][k][1] = __halves2half2(__float2half_rn(a2), __float2half_rn(a3));
        }
    }
    // normalize post-pass (register-only)
    #pragma unroll
    for (int p = 0; p < RPT; ++p) {
        const float i0 = 1.f / s[p][0], i1 = 1.f / s[p][1];
        const float i2 = 1.f / s[p][2], i3 = 1.f / s[p][3];
        #pragma unroll
        for (int k = 0; k < 9; ++k) {
            wh[p][k][0] = __halves2half2(
                __float2half_rn(__low2float (wh[p][k][0]) * i0),
                __float2half_rn(__high2float(wh[p][k][0]) * i1));
            wh[p][k][1] = __halves2half2(
                __float2half_rn(__low2float (wh[p][k][1]) * i2),
                __float2half_rn(__high2float(wh[p][k][1]) * i3));
        }
    }

    // ---- 8 fused steps; publish, bar, read, COMPUTE, bar ----
    #pragma unroll 1
    for (int st = 0; st < NSTEP; ++st) {
        *reinterpret_cast<float4*>(&ldsT[rg][j0]) = xr[0];
        *reinterpret_cast<float4*>(&ldsB[rg][j0]) = xr[RPT - 1];
        __syncthreads();
        float4 up = make_float4(0.f, 0.f, 0.f, 0.f);   // row r0-1
        float4 dn = make_float4(0.f, 0.f, 0.f, 0.f);   // row r0+3
        if (rg > 0)       up = *reinterpret_cast<const float4*>(&ldsB[rg - 1][j0]);
        if (rg < NRG - 1) dn = *reinterpret_cast<const float4*>(&ldsT[rg + 1][j0]);

        // compute INSIDE the read-protected region: reads are consumed here,
        // hence drained before the barrier below that precedes next publish.
        float win[3][6];
        MKWIN(win[0], up);       // input row r0-1
        MKWIN(win[1], xr[0]);    // input row r0
        #pragma unroll
        for (int p = 0; p < RPT; ++p) {
            if (p < RPT - 1) { MKWIN(win[(p + 2) % 3], xr[p + 1]); }
            else             { MKWIN(win[(p + 2) % 3], dn); }
            float a0 = 0.f, a1 = 0.f, a2 = 0.f, a3 = 0.f;
            #pragma unroll
            for (int di = 0; di < 3; ++di) {
                #pragma unroll
                for (int dj = 0; dj < 3; ++dj) {
                    const int k = di * 3 + dj;
                    const __half2 w0 = wh[p][k][0];
                    const __half2 w1 = wh[p][k][1];
                    a0 = fmaf(__low2float (w0), win[(p + di) % 3][dj + 0], a0);
                    a1 = fmaf(__high2float(w0), win[(p + di) % 3][dj + 1], a1);
                    a2 = fmaf(__low2float (w1), win[(p + di) % 3][dj + 2], a2);
                    a3 = fmaf(__high2float(w1), win[(p + di) % 3][dj + 3], a3);
                }
            }
            xr[p] = make_float4(a0, a1, a2, a3);
        }
        // re-impose zero padding (keeps pad rows 0 every step)
        #pragma unroll
        for (int p = 0; p < RPT; ++p) {
            const int gr = r0 + p;
            if ((unsigned)gr >= (unsigned)H)
                xr[p] = make_float4(0.f, 0.f, 0.f, 0.f);
        }
        // separates this step's reads from next step's publishes.
        // Last step: nothing is published after, drop it.
        if (st < NSTEP - 1)
            __syncthreads();
    }

    // ---- store owned rows only (coalesced float4) ----
    float* __restrict__ op = out + pbase;
    #pragma unroll
    for (int p = 0; p < RPT; ++p) {
        const int gr = r0 + p;
        const int lr = gr - qtr * OWN;
        if ((unsigned)lr < (unsigned)OWN)
            *reinterpret_cast<float4*>(op + gr * W + j0) = xr[p];
    }
}

extern "C" void kernel_launch(void* const* d_in, const int* in_sizes, int n_in,
                              void* d_out, int out_size, void* d_ws, size_t ws_size,
                              hipStream_t stream)
{
    const float* x = (const float*)d_in[0];
    const float* w = (const float*)d_in[1];
    float* out = (float*)d_out;
    (void)d_ws; (void)ws_size; (void)in_sizes; (void)n_in; (void)out_size;

    // 1024 blocks = 4 per plane (4n x 64c), 512 threads
    diff_fused<<<dim3(4 * 4 * 64), dim3(512), 0, stream>>>(x, w, out);
}

// Round 11
// 245.987 us; speedup vs baseline: 1.0675x; 1.0123x over previous
//
#include <hip/hip_runtime.h>
#include <hip/hip_fp16.h>

// Fused 8-step diffusion, v12: v11 + single-barrier double-buffered exchange,
// fenced against compiler motion.
//
// v11 post-mortem: neutral (89-90 vs v8's 88.2). VALU-counter attribution:
// step phase ~30-35us wall but only ~17us VALU-issue -> 13-15us of non-VALU
// step slack; load ~50-55us vs 38us warm floor (L3-service-bound, v7).
// Remaining untried step lever: barrier COUNT (v11 has 15/8 steps).
//
// v12: one barrier/step via double-buffered boundary rows.
//   publish buf[st&1] -> fence/BAR/fence -> read buf[st&1] -> compute.
// Writes to a buffer happen TWO fenced barriers after the reads of it.
// v3 raced with a cousin of this structure (v2 ran it spill-serialized and
// passed -> spill masked the race); suspected cause: codegen moving an LDS
// op across the barrier (cf. guide rule #18). Defense here:
// __builtin_amdgcn_sched_barrier(0) immediately BEFORE and AFTER every
// __syncthreads() -- no instruction may cross in either direction.
// 8 barriers instead of 15; waves may drift within an iteration so one
// wave's compute overlaps another's publish+read. Exchange values are
// bitwise identical to v11.
//
// Carried (v8/v11 frontier): 1024 blocks = 4/plane (48-row window = 32 owned
// + 8 halo each side), 512 threads, 3 rows x 4 cols/thread, k-outer
// independent weight stream packed |.| fp16 unnormalized + register
// normalize post-pass, x loads hoisted, XCD-chunked bijective swizzle,
// plain launch_bounds(512) (only shape escaping the 64-VGPR allocator trap).

constexpr int H = 128, W = 128, PLANE = H * W;
constexpr int NSTEP = 8;
constexpr int RPT  = 3;            // rows per thread (48-row window / 16 rg)
constexpr int NRG  = 16;
constexpr int HALO = 8;
constexpr int OWN  = 32;           // owned rows per block (4 blocks/plane)

// 6-wide column window (cols j0-1 .. j0+4) from a float4 row segment
#define MKWIN(D, V) do {                                                     \
    (D)[1] = (V).x; (D)[2] = (V).y; (D)[3] = (V).z; (D)[4] = (V).w;          \
    float _l = __shfl_up((V).w, 1);                                          \
    float _r = __shfl_down((V).x, 1);                                        \
    (D)[0] = (quad == 0)  ? 0.f : _l;                                        \
    (D)[5] = (quad == 31) ? 0.f : _r;                                        \
} while (0)

__global__ __launch_bounds__(512)
void diff_fused(const float* __restrict__ xin,
                const float* __restrict__ wgt,
                float* __restrict__ out)
{
    // double-buffered boundary rows (32 KB)
    __shared__ float ldsT[2][NRG][W];
    __shared__ float ldsB[2][NRG][W];

    const int tid   = threadIdx.x;
    const int quad  = tid & 31;         // cols 4q..4q+3
    const int rg    = tid >> 5;         // 0..15
    const int j0    = quad * 4;

    // XCD-chunked swizzle: hw block i -> logical (i&7)*128 + (i>>3).
    const int lb    = (blockIdx.x & 7) * 128 + (blockIdx.x >> 3);
    const int plane = lb >> 2;
    const int qtr   = lb & 3;
    const int rbase = qtr * OWN - HALO;         // window start row
    const int r0    = rbase + rg * RPT;         // this thread's first row
    const size_t pbase = (size_t)plane * PLANE;

    const float* __restrict__ xp = xin + pbase;
    const float* __restrict__ wb = wgt + pbase * 9;

    // ---- x window first: 3 independent misses in flight early ----
    float4 xr[RPT];
    #pragma unroll
    for (int p = 0; p < RPT; ++p) {
        const int gr = r0 + p;
        xr[p] = make_float4(0.f, 0.f, 0.f, 0.f);
        if ((unsigned)gr < (unsigned)H)
            xr[p] = *reinterpret_cast<const float4*>(xp + gr * W + j0);
    }

    // ---- weights: k-outer, pack |.| fp16 UNNORMALIZED as loads arrive,
    //      fp32 sums on the side; register-only normalize post-pass. ----
    __half2 wh[RPT][9][2];              // 54 VGPRs
    float s[RPT][4];
    #pragma unroll
    for (int p = 0; p < RPT; ++p) { s[p][0] = s[p][1] = s[p][2] = s[p][3] = 0.f; }

    #pragma unroll
    for (int k = 0; k < 9; ++k) {
        float4 v[RPT];
        #pragma unroll
        for (int p = 0; p < RPT; ++p) {
            const int gr = r0 + p;
            v[p] = make_float4(1.f, 1.f, 1.f, 1.f);      // dummy for pad rows
            if ((unsigned)gr < (unsigned)H)
                v[p] = *reinterpret_cast<const float4*>(
                           wb + (size_t)k * PLANE + gr * W + j0);
        }
        #pragma unroll
        for (int p = 0; p < RPT; ++p) {
            const float a0 = fabsf(v[p].x), a1 = fabsf(v[p].y);
            const float a2 = fabsf(v[p].z), a3 = fabsf(v[p].w);
            s[p][0] += a0; s[p][1] += a1; s[p][2] += a2; s[p][3] += a3;
            wh[p][k][0] = __halves2half2(__float2half_rn(a0), __float2half_rn(a1));
            wh[p][k][1] = __halves2half2(__float2half_rn(a2), __float2half_rn(a3));
        }
    }
    // normalize post-pass (register-only)
    #pragma unroll
    for (int p = 0; p < RPT; ++p) {
        const float i0 = 1.f / s[p][0], i1 = 1.f / s[p][1];
        const float i2 = 1.f / s[p][2], i3 = 1.f / s[p][3];
        #pragma unroll
        for (int k = 0; k < 9; ++k) {
            wh[p][k][0] = __halves2half2(
                __float2half_rn(__low2float (wh[p][k][0]) * i0),
                __float2half_rn(__high2float(wh[p][k][0]) * i1));
            wh[p][k][1] = __halves2half2(
                __float2half_rn(__low2float (wh[p][k][1]) * i2),
                __float2half_rn(__high2float(wh[p][k][1]) * i3));
        }
    }

    // ---- 8 fused steps; ONE fenced barrier per step ----
    #pragma unroll 1
    for (int st = 0; st < NSTEP; ++st) {
        const int buf = st & 1;
        *reinterpret_cast<float4*>(&ldsT[buf][rg][j0]) = xr[0];
        *reinterpret_cast<float4*>(&ldsB[buf][rg][j0]) = xr[RPT - 1];
        __builtin_amdgcn_sched_barrier(0);   // nothing crosses the barrier
        __syncthreads();
        __builtin_amdgcn_sched_barrier(0);
        float4 up = make_float4(0.f, 0.f, 0.f, 0.f);   // row r0-1
        float4 dn = make_float4(0.f, 0.f, 0.f, 0.f);   // row r0+3
        if (rg > 0)       up = *reinterpret_cast<const float4*>(&ldsB[buf][rg - 1][j0]);
        if (rg < NRG - 1) dn = *reinterpret_cast<const float4*>(&ldsT[buf][rg + 1][j0]);

        // reads are consumed here; writes to buf recur two fenced barriers
        // later (iteration st+2), so read-vs-write separation holds.
        float win[3][6];
        MKWIN(win[0], up);       // input row r0-1
        MKWIN(win[1], xr[0]);    // input row r0
        #pragma unroll
        for (int p = 0; p < RPT; ++p) {
            if (p < RPT - 1) { MKWIN(win[(p + 2) % 3], xr[p + 1]); }
            else             { MKWIN(win[(p + 2) % 3], dn); }
            float a0 = 0.f, a1 = 0.f, a2 = 0.f, a3 = 0.f;
            #pragma unroll
            for (int di = 0; di < 3; ++di) {
                #pragma unroll
                for (int dj = 0; dj < 3; ++dj) {
                    const int k = di * 3 + dj;
                    const __half2 w0 = wh[p][k][0];
                    const __half2 w1 = wh[p][k][1];
                    a0 = fmaf(__low2float (w0), win[(p + di) % 3][dj + 0], a0);
                    a1 = fmaf(__high2float(w0), win[(p + di) % 3][dj + 1], a1);
                    a2 = fmaf(__low2float (w1), win[(p + di) % 3][dj + 2], a2);
                    a3 = fmaf(__high2float(w1), win[(p + di) % 3][dj + 3], a3);
                }
            }
            xr[p] = make_float4(a0, a1, a2, a3);
        }
        // re-impose zero padding (keeps pad rows 0 every step)
        #pragma unroll
        for (int p = 0; p < RPT; ++p) {
            const int gr = r0 + p;
            if ((unsigned)gr >= (unsigned)H)
                xr[p] = make_float4(0.f, 0.f, 0.f, 0.f);
        }
    }

    // ---- store owned rows only (coalesced float4) ----
    float* __restrict__ op = out + pbase;
    #pragma unroll
    for (int p = 0; p < RPT; ++p) {
        const int gr = r0 + p;
        const int lr = gr - qtr * OWN;
        if ((unsigned)lr < (unsigned)OWN)
            *reinterpret_cast<float4*>(op + gr * W + j0) = xr[p];
    }
}

extern "C" void kernel_launch(void* const* d_in, const int* in_sizes, int n_in,
                              void* d_out, int out_size, void* d_ws, size_t ws_size,
                              hipStream_t stream)
{
    const float* x = (const float*)d_in[0];
    const float* w = (const float*)d_in[1];
    float* out = (float*)d_out;
    (void)d_ws; (void)ws_size; (void)in_sizes; (void)n_in; (void)out_size;

    // 1024 blocks = 4 per plane (4n x 64c), 512 threads
    diff_fused<<<dim3(4 * 4 * 64), dim3(512), 0, stream>>>(x, w, out);
}